// Round 20
// baseline (64.802 us; speedup 1.0000x reference)
//
#include <hip/hip_runtime.h>
#include <math.h>

#define NB 4
#define NV 4096
#define DIN 3072
#define HD 64
#define CAP 80

typedef unsigned short u16;
typedef unsigned int u32;
typedef _Float16 h2 __attribute__((ext_vector_type(2)));

__device__ __forceinline__ float fdot2u(u32 v, u32 q, float c) {
#if __has_builtin(__builtin_amdgcn_fdot2)
  return __builtin_amdgcn_fdot2(__builtin_bit_cast(h2, v), __builtin_bit_cast(h2, q), c, false);
#else
  h2 a = __builtin_bit_cast(h2, v), b = __builtin_bit_cast(h2, q);
  return c + (float)a[0] * (float)b[0] + (float)a[1] * (float)b[1];
#endif
}

__device__ __forceinline__ h2 shx(h2 v, int off) {
  return __builtin_bit_cast(h2, (u32)__shfl_xor((int)__builtin_bit_cast(u32, v), off, 64));
}

// ---------------- kernel0: encoder stage A (partial GEMV over k-chunks)
__global__ __launch_bounds__(256) void enc_a_kernel(const float* __restrict__ stim,
                                                    const float* __restrict__ W1,
                                                    float* __restrict__ part) {
  int c = blockIdx.x;  // 24 k-chunks
  int b = blockIdx.y;  // 4 batches
  int t = threadIdx.x;
  int j = t & 127, h = t >> 7;
  int k0 = c * 128 + h * 64;
  float acc = 0.f;
#pragma unroll 8
  for (int k = 0; k < 64; ++k)
    acc += stim[b * DIN + k0 + k] * W1[(size_t)(k0 + k) * 128 + j];
  part[((b * 24 + c) * 2 + h) * 128 + j] = acc;
}

// ---------------- mid: csr build (blocks 0..NV-1) || whsk1+enc_b (blocks NV..NV+511)
// whsk1 compute hides under csr's HBM stream (no inter-branch dependency).
__global__ __launch_bounds__(256) void mid_kernel(
    const float* __restrict__ adj, int* __restrict__ cnt, int* __restrict__ cols,
    const float* __restrict__ part, const float* __restrict__ b1,
    const float* __restrict__ lng, const float* __restrict__ lnb,
    const float* __restrict__ W2, const float* __restrict__ b2,
    const float* __restrict__ emb, const float* __restrict__ Wg,
    const float* __restrict__ Sw, const float* __restrict__ Sb,
    u16* __restrict__ Whh, float* __restrict__ Sk) {
  __shared__ __align__(16) char smem[42784];
  int bid = blockIdx.x;
  int t = threadIdx.x;
  if (bid < NV) {
    // ---- csr: deterministic neighbor-list; shuffle prefix-scan; zero-filled tail
    int* wtot = (int*)smem;
    int* stot = (int*)(smem + 16);
    int row = bid;
    int l = t & 63, w = t >> 6;
    const float4* p = (const float4*)(adj + (size_t)row * NV);
    float4 v0 = p[t], v1 = p[t + 256], v2 = p[t + 512], v3 = p[t + 768];
    int c = (v0.x > 0.f) + (v0.y > 0.f) + (v0.z > 0.f) + (v0.w > 0.f) +
            (v1.x > 0.f) + (v1.y > 0.f) + (v1.z > 0.f) + (v1.w > 0.f) +
            (v2.x > 0.f) + (v2.y > 0.f) + (v2.z > 0.f) + (v2.w > 0.f) +
            (v3.x > 0.f) + (v3.y > 0.f) + (v3.z > 0.f) + (v3.w > 0.f);
    int val = c;
#pragma unroll
    for (int off = 1; off < 64; off <<= 1) {
      int tmp = __shfl_up(val, off, 64);
      if (l >= off) val += tmp;
    }
    if (l == 63) wtot[w] = val;
    __syncthreads();
    int base = 0;
    for (int i = 0; i < w; ++i) base += wtot[i];
    if (t == 255) {
      int s = base + val;
      s = s > CAP ? CAP : s;
      cnt[row] = s;
      *stot = s;
    }
    int o = base + (val - c);
    int* cr = cols + row * CAP;
#define EMIT(vv, jj) if ((vv) > 0.f) { if (o < CAP) cr[o] = (jj); ++o; }
    int j0 = t * 4, j1 = (t + 256) * 4, j2 = (t + 512) * 4, j3 = (t + 768) * 4;
    EMIT(v0.x, j0) EMIT(v0.y, j0 + 1) EMIT(v0.z, j0 + 2) EMIT(v0.w, j0 + 3)
    EMIT(v1.x, j1) EMIT(v1.y, j1 + 1) EMIT(v1.z, j1 + 2) EMIT(v1.w, j1 + 3)
    EMIT(v2.x, j2) EMIT(v2.y, j2 + 1) EMIT(v2.z, j2 + 2) EMIT(v2.w, j2 + 3)
    EMIT(v3.x, j3) EMIT(v3.y, j3 + 1) EMIT(v3.z, j3 + 2) EMIT(v3.w, j3 + 3)
#undef EMIT
    __syncthreads();
    if (t < CAP && t >= *stot) cr[t] = 0;  // valid row id; p==0 masks it in attn
  } else {
    // ---- whsk1 with enc_b recomputed per block (deterministic, identical per block)
    float* wgt = (float*)smem;               // 16384 B
    float* swt = (float*)(smem + 16384);     // 16384 B
    float* xst = (float*)(smem + 32768);     // 8448 B
    float* sbs = (float*)(smem + 41216);     // 256 B
    float* act = (float*)(smem + 41472);     // 512 B
    float* red = (float*)(smem + 41984);     // 512 B
    float* gs  = (float*)(smem + 42496);     // 256 B
    float* s_mu = (float*)(smem + 42752);
    float* s_var = (float*)(smem + 42756);
    int tid = t;
    int base = (bid - NV) * 32;  // 32 rows per block; all same batch
    int b = base >> 12;

    for (int i = tid; i < 1024; i += 256) {
      ((float4*)wgt)[i] = ((const float4*)Wg)[i];
      ((float4*)swt)[i] = ((const float4*)Sw)[i];
    }
    if (tid < 64) sbs[tid] = Sb[tid];
    if (tid < 128) {
      float hv = 0.f;
      for (int c = 0; c < 48; ++c) hv += part[(b * 48 + c) * 128 + tid];
      hv += b1[tid];
      act[tid] = hv;
      red[tid] = hv;
    }
    __syncthreads();
    for (int s = 64; s > 0; s >>= 1) {
      if (tid < s) red[tid] += red[tid + s];
      __syncthreads();
    }
    if (tid == 0) *s_mu = red[0] * (1.f / 128.f);
    __syncthreads();
    if (tid < 128) { float dv = act[tid] - *s_mu; red[tid] = dv * dv; }
    __syncthreads();
    for (int s = 64; s > 0; s >>= 1) {
      if (tid < s) red[tid] += red[tid + s];
      __syncthreads();
    }
    if (tid == 0) *s_var = red[0] * (1.f / 128.f);
    __syncthreads();
    if (tid < 128) {
      float y = (act[tid] - *s_mu) * rsqrtf(*s_var + 1e-5f) * lng[tid] + lnb[tid];
      act[tid] = 0.5f * y * (1.f + erff(y * 0.70710678118f));  // exact GELU
    }
    __syncthreads();
    if (tid < 64) {
      float a2 = 0.f;
      for (int k = 0; k < 128; ++k) a2 += act[k] * W2[k * 64 + tid];
      gs[tid] = a2 + b2[tid];
    }
    __syncthreads();
    for (int i4 = tid; i4 < 512; i4 += 256) {
      int rr = i4 >> 4, k0 = (i4 & 15) * 4;
      int n = (base + rr) & (NV - 1);
      float4 gv = *(const float4*)(gs + k0);
      float4 ev = *(const float4*)(emb + (size_t)n * 64 + k0);
      xst[(k0 + 0) * 33 + rr] = gv.x + ev.x;
      xst[(k0 + 1) * 33 + rr] = gv.y + ev.y;
      xst[(k0 + 2) * 33 + rr] = gv.z + ev.z;
      xst[(k0 + 3) * 33 + rr] = gv.w + ev.w;
    }
    __syncthreads();
    int cg = tid & 15;
    int r0 = tid >> 4;
    float4 aw0 = make_float4(0, 0, 0, 0), as0 = make_float4(0, 0, 0, 0);
    float4 aw1 = make_float4(0, 0, 0, 0), as1 = make_float4(0, 0, 0, 0);
#pragma unroll 4
    for (int k = 0; k < 64; ++k) {
      float4 wv = *(const float4*)&wgt[k * 64 + 4 * cg];
      float4 sv = *(const float4*)&swt[k * 64 + 4 * cg];
      float x0 = xst[k * 33 + r0];
      float x1v = xst[k * 33 + r0 + 16];
      aw0.x = fmaf(x0, wv.x, aw0.x); aw0.y = fmaf(x0, wv.y, aw0.y);
      aw0.z = fmaf(x0, wv.z, aw0.z); aw0.w = fmaf(x0, wv.w, aw0.w);
      as0.x = fmaf(x0, sv.x, as0.x); as0.y = fmaf(x0, sv.y, as0.y);
      as0.z = fmaf(x0, sv.z, as0.z); as0.w = fmaf(x0, sv.w, as0.w);
      aw1.x = fmaf(x1v, wv.x, aw1.x); aw1.y = fmaf(x1v, wv.y, aw1.y);
      aw1.z = fmaf(x1v, wv.z, aw1.z); aw1.w = fmaf(x1v, wv.w, aw1.w);
      as1.x = fmaf(x1v, sv.x, as1.x); as1.y = fmaf(x1v, sv.y, as1.y);
      as1.z = fmaf(x1v, sv.z, as1.z); as1.w = fmaf(x1v, sv.w, as1.w);
    }
    float4 sb4 = *(const float4*)&sbs[4 * cg];
    int grow0 = base + r0, grow1 = base + r0 + 16;
    ushort4 h0, h1;
    h0.x = __builtin_bit_cast(u16, (_Float16)aw0.x);
    h0.y = __builtin_bit_cast(u16, (_Float16)aw0.y);
    h0.z = __builtin_bit_cast(u16, (_Float16)aw0.z);
    h0.w = __builtin_bit_cast(u16, (_Float16)aw0.w);
    h1.x = __builtin_bit_cast(u16, (_Float16)aw1.x);
    h1.y = __builtin_bit_cast(u16, (_Float16)aw1.y);
    h1.z = __builtin_bit_cast(u16, (_Float16)aw1.z);
    h1.w = __builtin_bit_cast(u16, (_Float16)aw1.w);
    *(ushort4*)(Whh + (size_t)grow0 * 64 + 4 * cg) = h0;
    *(ushort4*)(Whh + (size_t)grow1 * 64 + 4 * cg) = h1;
    *(float4*)(Sk + (size_t)grow0 * 64 + 4 * cg) =
        make_float4(as0.x + sb4.x, as0.y + sb4.y, as0.z + sb4.z, as0.w + sb4.w);
    *(float4*)(Sk + (size_t)grow1 * 64 + 4 * cg) =
        make_float4(as1.x + sb4.x, as1.y + sb4.y, as1.z + sb4.z, as1.w + sb4.w);
  }
}

// ---------------- attn layer1 fused with whsk2 (r19 structure + tail-guarded exp)
__global__ __launch_bounds__(512) void attn_l1_kernel(
    const u16* __restrict__ Whh, const float* __restrict__ Sk,
    const int* __restrict__ cnt, const int* __restrict__ cols,
    const float* __restrict__ Wg2, const float* __restrict__ Sw2, const float* __restrict__ Sb2,
    u16* __restrict__ Whh2, float* __restrict__ Sk2) {
  __shared__ float wgt[4096];
  __shared__ float swt[4096];
  __shared__ float sbs[64];
  __shared__ float xl[8][64];
  int tid = threadIdx.x;
  int lane = tid & 63;
  int w = tid >> 6;  // 0..7
  int bid = blockIdx.x;
  int x = bid & 7;
  int gidx = bid >> 3;  // 0..255
  int b = x >> 1;
  int rowhalf = x & 1;
  int n = __builtin_amdgcn_readfirstlane(rowhalf * 2048 + gidx * 8 + w);
  int wid = b * NV + n;
  const u16* whhbase = Whh + (size_t)b * (NV * HD);
  int nn = __builtin_amdgcn_readfirstlane(cnt[n]);
  const int* cl = cols + n * CAP;
  int q = lane & 3;
  int gq = lane >> 2;

  for (int i = tid; i < 1024; i += 512) {
    ((float4*)wgt)[i] = ((const float4*)Wg2)[i];
    ((float4*)swt)[i] = ((const float4*)Sw2)[i];
  }
  if (tid < 64) sbs[tid] = Sb2[tid];

  const uint4* qr = (const uint4*)(whhbase + (size_t)n * HD);
  uint4 QA = qr[q];
  uint4 QB = qr[q + 4];

  float s[5], p[5];
  uint4 SA0, SB0, SA1, SB1, SA2, SB2;
#define SCORE_BLOCK(jb, SAv, SBv)                                                                \
  {                                                                                              \
    int j = (jb) * 16 + gq;                                                                      \
    int m = cl[j];                                                                               \
    const uint4* vr = (const uint4*)(whhbase + (size_t)m * HD);                                  \
    SAv = vr[q];                                                                                 \
    SBv = vr[q + 4];                                                                             \
    float t = 0.f;                                                                               \
    t = fdot2u(SAv.x, QA.x, t);                                                                  \
    t = fdot2u(SAv.y, QA.y, t);                                                                  \
    t = fdot2u(SAv.z, QA.z, t);                                                                  \
    t = fdot2u(SAv.w, QA.w, t);                                                                  \
    t = fdot2u(SBv.x, QB.x, t);                                                                  \
    t = fdot2u(SBv.y, QB.y, t);                                                                  \
    t = fdot2u(SBv.z, QB.z, t);                                                                  \
    t = fdot2u(SBv.w, QB.w, t);                                                                  \
    t += __shfl_xor(t, 1, 64);                                                                   \
    t += __shfl_xor(t, 2, 64);                                                                   \
    s[jb] = (j < nn) ? t * 0.125f : -1e30f;                                                      \
  }
  SCORE_BLOCK(0, SA0, SB0)
  SCORE_BLOCK(1, SA1, SB1)
  SCORE_BLOCK(2, SA2, SB2)
  s[3] = -1e30f;
  s[4] = -1e30f;
  bool tail = (nn > 48);
  if (tail) {
    uint4 TA, TB;
    SCORE_BLOCK(3, TA, TB)
    SCORE_BLOCK(4, TA, TB)
  }
#undef SCORE_BLOCK

  float mx = fmaxf(fmaxf(fmaxf(s[0], s[1]), fmaxf(s[2], s[3])), s[4]);
  mx = fmaxf(mx, __shfl_xor(mx, 4, 64));
  mx = fmaxf(mx, __shfl_xor(mx, 8, 64));
  mx = fmaxf(mx, __shfl_xor(mx, 16, 64));
  mx = fmaxf(mx, __shfl_xor(mx, 32, 64));
  float sum = 0.f;
#pragma unroll
  for (int jb = 0; jb < 3; ++jb) {
    p[jb] = (jb * 16 + gq < nn) ? __expf(s[jb] - mx) : 0.f;
    sum += p[jb];
  }
  p[3] = 0.f;
  p[4] = 0.f;
  if (tail) {
    p[3] = (48 + gq < nn) ? __expf(s[3] - mx) : 0.f;
    p[4] = (64 + gq < nn) ? __expf(s[4] - mx) : 0.f;
    sum += p[3] + p[4];
  }
  sum += __shfl_xor(sum, 4, 64);
  sum += __shfl_xor(sum, 8, 64);
  sum += __shfl_xor(sum, 16, 64);
  sum += __shfl_xor(sum, 32, 64);
  float inv = 1.f / sum;

  h2 aa[8];
#pragma unroll
  for (int k = 0; k < 8; ++k) aa[k] = h2{(_Float16)0, (_Float16)0};
#define PV_ACC(pp, Av, Bv)                                                                       \
  {                                                                                              \
    _Float16 pf = (_Float16)(pp);                                                                \
    h2 ph = {pf, pf};                                                                            \
    aa[0] += __builtin_bit_cast(h2, (Av).x) * ph;                                                \
    aa[1] += __builtin_bit_cast(h2, (Av).y) * ph;                                                \
    aa[2] += __builtin_bit_cast(h2, (Av).z) * ph;                                                \
    aa[3] += __builtin_bit_cast(h2, (Av).w) * ph;                                                \
    aa[4] += __builtin_bit_cast(h2, (Bv).x) * ph;                                                \
    aa[5] += __builtin_bit_cast(h2, (Bv).y) * ph;                                                \
    aa[6] += __builtin_bit_cast(h2, (Bv).z) * ph;                                                \
    aa[7] += __builtin_bit_cast(h2, (Bv).w) * ph;                                                \
  }
  PV_ACC(p[0], SA0, SB0)
  PV_ACC(p[1], SA1, SB1)
  PV_ACC(p[2], SA2, SB2)
  if (tail) {
    int m3 = cl[48 + gq];
    const uint4* vr3 = (const uint4*)(whhbase + (size_t)m3 * HD);
    uint4 A3 = vr3[q], B3 = vr3[q + 4];
    PV_ACC(p[3], A3, B3)
    if (nn > 64) {
      int m4 = cl[64 + gq];
      const uint4* vr4 = (const uint4*)(whhbase + (size_t)m4 * HD);
      uint4 A4 = vr4[q], B4 = vr4[q + 4];
      PV_ACC(p[4], A4, B4)
    }
  }
#undef PV_ACC

  bool g1 = (gq & 1) != 0;
  h2 bb[4];
#pragma unroll
  for (int i = 0; i < 4; ++i) {
    h2 k = g1 ? aa[i + 4] : aa[i];
    h2 u = g1 ? aa[i] : aa[i + 4];
    bb[i] = k + shx(u, 4);
  }
  bool g2 = (gq & 2) != 0;
  h2 cc[2];
#pragma unroll
  for (int i = 0; i < 2; ++i) {
    h2 k = g2 ? bb[i + 2] : bb[i];
    h2 u = g2 ? bb[i] : bb[i + 2];
    cc[i] = k + shx(u, 8);
  }
  bool g4 = (gq & 4) != 0;
  h2 dd;
  {
    h2 k = g4 ? cc[1] : cc[0];
    h2 u = g4 ? cc[0] : cc[1];
    dd = k + shx(u, 16);
  }
  dd = dd + shx(dd, 32);
  int a = 8 * q + 32 * (gq & 1) + 4 * ((gq >> 1) & 1) + 2 * ((gq >> 2) & 1);
  float f0 = (float)dd[0] * inv;
  float f1 = (float)dd[1] * inv;

  float2 sk2 = *(const float2*)(Sk + (size_t)wid * HD + a);
  float o0 = (f0 > 0.f ? f0 : (__expf(f0) - 1.f)) + sk2.x;
  float o1 = (f1 > 0.f ? f1 : (__expf(f1) - 1.f)) + sk2.y;
  if ((gq & 8) == 0) {
    xl[w][a] = o0;
    xl[w][a + 1] = o1;
  }
  __syncthreads();

  // ---- whsk2 tail: 2 waves compute Whh2/Sk2 for the block's 8 rows
  if (tid < 128) {
    int cg = tid & 15;
    int r = tid >> 4;
    float4 aw = make_float4(0, 0, 0, 0), as = make_float4(0, 0, 0, 0);
#pragma unroll 4
    for (int k = 0; k < 64; ++k) {
      float4 wv = *(const float4*)&wgt[k * 64 + 4 * cg];
      float4 sv = *(const float4*)&swt[k * 64 + 4 * cg];
      float xv = xl[r][k];
      aw.x = fmaf(xv, wv.x, aw.x); aw.y = fmaf(xv, wv.y, aw.y);
      aw.z = fmaf(xv, wv.z, aw.z); aw.w = fmaf(xv, wv.w, aw.w);
      as.x = fmaf(xv, sv.x, as.x); as.y = fmaf(xv, sv.y, as.y);
      as.z = fmaf(xv, sv.z, as.z); as.w = fmaf(xv, sv.w, as.w);
    }
    int n_r = rowhalf * 2048 + gidx * 8 + r;
    size_t wid_r = (size_t)(b * NV + n_r) * 64 + 4 * cg;
    float4 sb4 = *(const float4*)&sbs[4 * cg];
    ushort4 hh;
    hh.x = __builtin_bit_cast(u16, (_Float16)aw.x);
    hh.y = __builtin_bit_cast(u16, (_Float16)aw.y);
    hh.z = __builtin_bit_cast(u16, (_Float16)aw.z);
    hh.w = __builtin_bit_cast(u16, (_Float16)aw.w);
    *(ushort4*)(Whh2 + wid_r) = hh;
    *(float4*)(Sk2 + wid_r) =
        make_float4(as.x + sb4.x, as.y + sb4.y, as.z + sb4.z, as.w + sb4.w);
  }
}

// ---------------- attn layer2 (r18 structure + tail-guarded exp): fused readout
__global__ __launch_bounds__(256) void attn_l2_kernel(
    const u16* __restrict__ Whh, const float* __restrict__ Sk,
    const int* __restrict__ cnt, const int* __restrict__ cols,
    const float* __restrict__ roW, const float* __restrict__ rob, float* __restrict__ out) {
  int tid = threadIdx.x;
  int lane = tid & 63;
  int w = tid >> 6;
  int bid = blockIdx.x;
  int x = bid & 7;
  int gidx = bid >> 3;
  int b = x >> 1;
  int n = __builtin_amdgcn_readfirstlane((x & 1) * 2048 + gidx * 4 + w);
  int wid = b * NV + n;
  const u16* whhbase = Whh + (size_t)b * (NV * HD);
  int nn = __builtin_amdgcn_readfirstlane(cnt[n]);
  const int* cl = cols + n * CAP;
  int q = lane & 3;
  int gq = lane >> 2;

  const uint4* qr = (const uint4*)(whhbase + (size_t)n * HD);
  uint4 QA = qr[q];
  uint4 QB = qr[q + 4];

  float s[5], p[5];
  uint4 SA0, SB0, SA1, SB1, SA2, SB2;
#define SCORE_BLOCK(jb, SAv, SBv)                                                                \
  {                                                                                              \
    int j = (jb) * 16 + gq;                                                                      \
    int m = cl[j];                                                                               \
    const uint4* vr = (const uint4*)(whhbase + (size_t)m * HD);                                  \
    SAv = vr[q];                                                                                 \
    SBv = vr[q + 4];                                                                             \
    float t = 0.f;                                                                               \
    t = fdot2u(SAv.x, QA.x, t);                                                                  \
    t = fdot2u(SAv.y, QA.y, t);                                                                  \
    t = fdot2u(SAv.z, QA.z, t);                                                                  \
    t = fdot2u(SAv.w, QA.w, t);                                                                  \
    t = fdot2u(SBv.x, QB.x, t);                                                                  \
    t = fdot2u(SBv.y, QB.y, t);                                                                  \
    t = fdot2u(SBv.z, QB.z, t);                                                                  \
    t = fdot2u(SBv.w, QB.w, t);                                                                  \
    t += __shfl_xor(t, 1, 64);                                                                   \
    t += __shfl_xor(t, 2, 64);                                                                   \
    s[jb] = (j < nn) ? t * 0.125f : -1e30f;                                                      \
  }
  SCORE_BLOCK(0, SA0, SB0)
  SCORE_BLOCK(1, SA1, SB1)
  SCORE_BLOCK(2, SA2, SB2)
  s[3] = -1e30f;
  s[4] = -1e30f;
  bool tail = (nn > 48);
  if (tail) {
    uint4 TA, TB;
    SCORE_BLOCK(3, TA, TB)
    SCORE_BLOCK(4, TA, TB)
  }
#undef SCORE_BLOCK

  float mx = fmaxf(fmaxf(fmaxf(s[0], s[1]), fmaxf(s[2], s[3])), s[4]);
  mx = fmaxf(mx, __shfl_xor(mx, 4, 64));
  mx = fmaxf(mx, __shfl_xor(mx, 8, 64));
  mx = fmaxf(mx, __shfl_xor(mx, 16, 64));
  mx = fmaxf(mx, __shfl_xor(mx, 32, 64));
  float sum = 0.f;
#pragma unroll
  for (int jb = 0; jb < 3; ++jb) {
    p[jb] = (jb * 16 + gq < nn) ? __expf(s[jb] - mx) : 0.f;
    sum += p[jb];
  }
  p[3] = 0.f;
  p[4] = 0.f;
  if (tail) {
    p[3] = (48 + gq < nn) ? __expf(s[3] - mx) : 0.f;
    p[4] = (64 + gq < nn) ? __expf(s[4] - mx) : 0.f;
    sum += p[3] + p[4];
  }
  sum += __shfl_xor(sum, 4, 64);
  sum += __shfl_xor(sum, 8, 64);
  sum += __shfl_xor(sum, 16, 64);
  sum += __shfl_xor(sum, 32, 64);
  float inv = 1.f / sum;

  h2 aa[8];
#pragma unroll
  for (int k = 0; k < 8; ++k) aa[k] = h2{(_Float16)0, (_Float16)0};
#define PV_ACC(pp, Av, Bv)                                                                       \
  {                                                                                              \
    _Float16 pf = (_Float16)(pp);                                                                \
    h2 ph = {pf, pf};                                                                            \
    aa[0] += __builtin_bit_cast(h2, (Av).x) * ph;                                                \
    aa[1] += __builtin_bit_cast(h2, (Av).y) * ph;                                                \
    aa[2] += __builtin_bit_cast(h2, (Av).z) * ph;                                                \
    aa[3] += __builtin_bit_cast(h2, (Av).w) * ph;                                                \
    aa[4] += __builtin_bit_cast(h2, (Bv).x) * ph;                                                \
    aa[5] += __builtin_bit_cast(h2, (Bv).y) * ph;                                                \
    aa[6] += __builtin_bit_cast(h2, (Bv).z) * ph;                                                \
    aa[7] += __builtin_bit_cast(h2, (Bv).w) * ph;                                                \
  }
  PV_ACC(p[0], SA0, SB0)
  PV_ACC(p[1], SA1, SB1)
  PV_ACC(p[2], SA2, SB2)
  if (tail) {
    int m3 = cl[48 + gq];
    const uint4* vr3 = (const uint4*)(whhbase + (size_t)m3 * HD);
    uint4 A3 = vr3[q], B3 = vr3[q + 4];
    PV_ACC(p[3], A3, B3)
    if (nn > 64) {
      int m4 = cl[64 + gq];
      const uint4* vr4 = (const uint4*)(whhbase + (size_t)m4 * HD);
      uint4 A4 = vr4[q], B4 = vr4[q + 4];
      PV_ACC(p[4], A4, B4)
    }
  }
#undef PV_ACC

  bool g1 = (gq & 1) != 0;
  h2 bb[4];
#pragma unroll
  for (int i = 0; i < 4; ++i) {
    h2 k = g1 ? aa[i + 4] : aa[i];
    h2 u = g1 ? aa[i] : aa[i + 4];
    bb[i] = k + shx(u, 4);
  }
  bool g2 = (gq & 2) != 0;
  h2 cc[2];
#pragma unroll
  for (int i = 0; i < 2; ++i) {
    h2 k = g2 ? bb[i + 2] : bb[i];
    h2 u = g2 ? bb[i] : bb[i + 2];
    cc[i] = k + shx(u, 8);
  }
  bool g4 = (gq & 4) != 0;
  h2 dd;
  {
    h2 k = g4 ? cc[1] : cc[0];
    h2 u = g4 ? cc[0] : cc[1];
    dd = k + shx(u, 16);
  }
  dd = dd + shx(dd, 32);
  int a = 8 * q + 32 * (gq & 1) + 4 * ((gq >> 1) & 1) + 2 * ((gq >> 2) & 1);
  float f0 = (float)dd[0] * inv;
  float f1 = (float)dd[1] * inv;

  float2 sk2 = *(const float2*)(Sk + (size_t)wid * HD + a);
  float2 ro2 = *(const float2*)(roW + a);
  float wsp = (f0 + sk2.x) * ro2.x + (f1 + sk2.y) * ro2.y;
  wsp += __shfl_xor(wsp, 1, 64);
  wsp += __shfl_xor(wsp, 2, 64);
  wsp += __shfl_xor(wsp, 4, 64);
  wsp += __shfl_xor(wsp, 8, 64);
  wsp += __shfl_xor(wsp, 16, 64);
  if (lane == 0) out[wid] = wsp + rob[0];
}

extern "C" void kernel_launch(void* const* d_in, const int* in_sizes, int n_in,
                              void* d_out, int out_size, void* d_ws, size_t ws_size,
                              hipStream_t stream) {
  const float* stim = (const float*)d_in[0];
  const float* adj  = (const float*)d_in[1];
  const float* W1   = (const float*)d_in[2];
  const float* b1   = (const float*)d_in[3];
  const float* lng  = (const float*)d_in[4];
  const float* lnb  = (const float*)d_in[5];
  const float* W2   = (const float*)d_in[6];
  const float* b2   = (const float*)d_in[7];
  const float* emb  = (const float*)d_in[8];
  const float* Wg1  = (const float*)d_in[9];
  const float* Wg2  = (const float*)d_in[10];
  const float* s1w  = (const float*)d_in[11];
  const float* s1b  = (const float*)d_in[12];
  const float* s2w  = (const float*)d_in[13];
  const float* s2b  = (const float*)d_in[14];
  const float* roW  = (const float*)d_in[15];
  const float* rob  = (const float*)d_in[16];
  float* out = (float*)d_out;

  char* ws = (char*)d_ws;
  float* part = (float*)(ws + 4096);       // 96 KB
  int*   cnt  = (int*)(ws + 131072);       // 4096 ints
  int*   cols = (int*)(ws + 147456);       // 4096*80 ints = 1.25 MB
  u16*   Whh2 = (u16*)(ws + 1572864);      // 2 MB  (layer2 f16 rows)
  float* Sk   = (float*)(ws + 5767168);    // 4 MB  (layer1 skip)
  float* Sk2  = (float*)(ws + 9961472);    // 4 MB  (layer2 skip)
  u16*   Whh  = (u16*)(ws + 14155776);     // 2 MB  (layer1 f16 rows)

  enc_a_kernel<<<dim3(24, 4), dim3(256), 0, stream>>>(stim, W1, part);
  mid_kernel<<<dim3(NV + 512), dim3(256), 0, stream>>>(adj, cnt, cols, part, b1, lng, lnb,
                                                       W2, b2, emb, Wg1, s1w, s1b, Whh, Sk);
  attn_l1_kernel<<<dim3(NB * NV / 8), dim3(512), 0, stream>>>(Whh, Sk, cnt, cols,
                                                              Wg2, s2w, s2b, Whh2, Sk2);
  attn_l2_kernel<<<dim3(NB * NV / 4), dim3(256), 0, stream>>>(Whh2, Sk2, cnt, cols,
                                                              roW, rob, out);
}

// Round 21
// 61.064 us; speedup vs baseline: 1.0612x; 1.0612x over previous
//
#include <hip/hip_runtime.h>
#include <math.h>

#define NB 4
#define NV 4096
#define DIN 3072
#define HD 64
#define CAP 80

typedef unsigned short u16;
typedef unsigned int u32;
typedef _Float16 h2 __attribute__((ext_vector_type(2)));

__device__ __forceinline__ float fdot2u(u32 v, u32 q, float c) {
#if __has_builtin(__builtin_amdgcn_fdot2)
  return __builtin_amdgcn_fdot2(__builtin_bit_cast(h2, v), __builtin_bit_cast(h2, q), c, false);
#else
  h2 a = __builtin_bit_cast(h2, v), b = __builtin_bit_cast(h2, q);
  return c + (float)a[0] * (float)b[0] + (float)a[1] * (float)b[1];
#endif
}

__device__ __forceinline__ h2 shx(h2 v, int off) {
  return __builtin_bit_cast(h2, (u32)__shfl_xor((int)__builtin_bit_cast(u32, v), off, 64));
}

// ---------------- fused: csr build (blocks 0..4095, tiny LDS) || enc_a (blocks 4096..4191)
__global__ __launch_bounds__(256) void pre_kernel(
    const float* __restrict__ adj, int* __restrict__ cnt, int* __restrict__ cols,
    const float* __restrict__ stim, const float* __restrict__ W1, float* __restrict__ part) {
  int bid = blockIdx.x;
  int t = threadIdx.x;
  if (bid < NV) {
    int row = bid;
    int l = t & 63, w = t >> 6;
    __shared__ int wtot[4];
    __shared__ int stot;
    const float4* p = (const float4*)(adj + (size_t)row * NV);
    float4 v0 = p[t], v1 = p[t + 256], v2 = p[t + 512], v3 = p[t + 768];
    int c = (v0.x > 0.f) + (v0.y > 0.f) + (v0.z > 0.f) + (v0.w > 0.f) +
            (v1.x > 0.f) + (v1.y > 0.f) + (v1.z > 0.f) + (v1.w > 0.f) +
            (v2.x > 0.f) + (v2.y > 0.f) + (v2.z > 0.f) + (v2.w > 0.f) +
            (v3.x > 0.f) + (v3.y > 0.f) + (v3.z > 0.f) + (v3.w > 0.f);
    int val = c;  // inclusive prefix within wave
#pragma unroll
    for (int off = 1; off < 64; off <<= 1) {
      int tmp = __shfl_up(val, off, 64);
      if (l >= off) val += tmp;
    }
    if (l == 63) wtot[w] = val;
    __syncthreads();
    int base = 0;
    for (int i = 0; i < w; ++i) base += wtot[i];
    if (t == 255) {
      int s = base + val;
      s = s > CAP ? CAP : s;
      cnt[row] = s;
      stot = s;
    }
    int o = base + (val - c);  // exclusive global prefix
    int* cr = cols + row * CAP;
#define EMIT(vv, jj) if ((vv) > 0.f) { if (o < CAP) cr[o] = (jj); ++o; }
    int j0 = t * 4, j1 = (t + 256) * 4, j2 = (t + 512) * 4, j3 = (t + 768) * 4;
    EMIT(v0.x, j0) EMIT(v0.y, j0 + 1) EMIT(v0.z, j0 + 2) EMIT(v0.w, j0 + 3)
    EMIT(v1.x, j1) EMIT(v1.y, j1 + 1) EMIT(v1.z, j1 + 2) EMIT(v1.w, j1 + 3)
    EMIT(v2.x, j2) EMIT(v2.y, j2 + 1) EMIT(v2.z, j2 + 2) EMIT(v2.w, j2 + 3)
    EMIT(v3.x, j3) EMIT(v3.y, j3 + 1) EMIT(v3.z, j3 + 2) EMIT(v3.w, j3 + 3)
#undef EMIT
    __syncthreads();
    if (t < CAP && t >= stot) cr[t] = 0;  // valid row id; p==0 masks it in attn
  } else {
    int e = bid - NV;
    int c = e % 24;  // k-chunk
    int b = e / 24;  // batch
    int j = t & 127, h = t >> 7;
    int k0 = c * 128 + h * 64;
    float acc = 0.f;
#pragma unroll 8
    for (int k = 0; k < 64; ++k)
      acc += stim[b * DIN + k0 + k] * W1[(size_t)(k0 + k) * 128 + j];
    part[((b * 24 + c) * 2 + h) * 128 + j] = acc;
  }
}

// ---------------- whsk1 with enc_b recomputed per block (deterministic, identical per block)
__global__ __launch_bounds__(256) void whsk1_kernel(
    const float* __restrict__ part, const float* __restrict__ b1,
    const float* __restrict__ lng, const float* __restrict__ lnb,
    const float* __restrict__ W2, const float* __restrict__ b2,
    const float* __restrict__ emb, const float* __restrict__ Wg,
    const float* __restrict__ Sw, const float* __restrict__ Sb,
    u16* __restrict__ Whh, float* __restrict__ Sk) {
  __shared__ float wgt[4096];
  __shared__ float swt[4096];
  __shared__ float xst[64 * 33];
  __shared__ float sbs[64];
  __shared__ float act[128];
  __shared__ float red[128];
  __shared__ __align__(16) float gs[64];
  __shared__ float s_mu, s_var;
  int tid = threadIdx.x;
  int base = blockIdx.x * 32;  // 32 rows per block; all same batch
  int b = base >> 12;

  for (int i = tid; i < 1024; i += 256) {
    ((float4*)wgt)[i] = ((const float4*)Wg)[i];
    ((float4*)swt)[i] = ((const float4*)Sw)[i];
  }
  if (tid < 64) sbs[tid] = Sb[tid];
  if (tid < 128) {
    float hv = 0.f;
    for (int c = 0; c < 48; ++c) hv += part[(b * 48 + c) * 128 + tid];
    hv += b1[tid];
    act[tid] = hv;
    red[tid] = hv;
  }
  __syncthreads();
  for (int s = 64; s > 0; s >>= 1) {
    if (tid < s) red[tid] += red[tid + s];
    __syncthreads();
  }
  if (tid == 0) s_mu = red[0] * (1.f / 128.f);
  __syncthreads();
  if (tid < 128) { float dv = act[tid] - s_mu; red[tid] = dv * dv; }
  __syncthreads();
  for (int s = 64; s > 0; s >>= 1) {
    if (tid < s) red[tid] += red[tid + s];
    __syncthreads();
  }
  if (tid == 0) s_var = red[0] * (1.f / 128.f);
  __syncthreads();
  if (tid < 128) {
    float y = (act[tid] - s_mu) * rsqrtf(s_var + 1e-5f) * lng[tid] + lnb[tid];
    act[tid] = 0.5f * y * (1.f + erff(y * 0.70710678118f));  // exact GELU
  }
  __syncthreads();
  if (tid < 64) {
    float a2 = 0.f;
    for (int k = 0; k < 128; ++k) a2 += act[k] * W2[k * 64 + tid];
    gs[tid] = a2 + b2[tid];
  }
  __syncthreads();
  for (int i4 = tid; i4 < 512; i4 += 256) {
    int rr = i4 >> 4, k0 = (i4 & 15) * 4;
    int n = (base + rr) & (NV - 1);
    float4 gv = *(const float4*)(gs + k0);
    float4 ev = *(const float4*)(emb + (size_t)n * 64 + k0);
    xst[(k0 + 0) * 33 + rr] = gv.x + ev.x;
    xst[(k0 + 1) * 33 + rr] = gv.y + ev.y;
    xst[(k0 + 2) * 33 + rr] = gv.z + ev.z;
    xst[(k0 + 3) * 33 + rr] = gv.w + ev.w;
  }
  __syncthreads();
  int cg = tid & 15;  // cols 4cg..4cg+3
  int r0 = tid >> 4;  // rows r0 and r0+16
  float4 aw0 = make_float4(0, 0, 0, 0), as0 = make_float4(0, 0, 0, 0);
  float4 aw1 = make_float4(0, 0, 0, 0), as1 = make_float4(0, 0, 0, 0);
#pragma unroll 4
  for (int k = 0; k < 64; ++k) {
    float4 wv = *(const float4*)&wgt[k * 64 + 4 * cg];
    float4 sv = *(const float4*)&swt[k * 64 + 4 * cg];
    float x0 = xst[k * 33 + r0];
    float x1v = xst[k * 33 + r0 + 16];
    aw0.x = fmaf(x0, wv.x, aw0.x); aw0.y = fmaf(x0, wv.y, aw0.y);
    aw0.z = fmaf(x0, wv.z, aw0.z); aw0.w = fmaf(x0, wv.w, aw0.w);
    as0.x = fmaf(x0, sv.x, as0.x); as0.y = fmaf(x0, sv.y, as0.y);
    as0.z = fmaf(x0, sv.z, as0.z); as0.w = fmaf(x0, sv.w, as0.w);
    aw1.x = fmaf(x1v, wv.x, aw1.x); aw1.y = fmaf(x1v, wv.y, aw1.y);
    aw1.z = fmaf(x1v, wv.z, aw1.z); aw1.w = fmaf(x1v, wv.w, aw1.w);
    as1.x = fmaf(x1v, sv.x, as1.x); as1.y = fmaf(x1v, sv.y, as1.y);
    as1.z = fmaf(x1v, sv.z, as1.z); as1.w = fmaf(x1v, sv.w, as1.w);
  }
  float4 sb4 = *(const float4*)&sbs[4 * cg];
  int grow0 = base + r0, grow1 = base + r0 + 16;
  ushort4 h0, h1;
  h0.x = __builtin_bit_cast(u16, (_Float16)aw0.x);
  h0.y = __builtin_bit_cast(u16, (_Float16)aw0.y);
  h0.z = __builtin_bit_cast(u16, (_Float16)aw0.z);
  h0.w = __builtin_bit_cast(u16, (_Float16)aw0.w);
  h1.x = __builtin_bit_cast(u16, (_Float16)aw1.x);
  h1.y = __builtin_bit_cast(u16, (_Float16)aw1.y);
  h1.z = __builtin_bit_cast(u16, (_Float16)aw1.z);
  h1.w = __builtin_bit_cast(u16, (_Float16)aw1.w);
  *(ushort4*)(Whh + (size_t)grow0 * 64 + 4 * cg) = h0;
  *(ushort4*)(Whh + (size_t)grow1 * 64 + 4 * cg) = h1;
  *(float4*)(Sk + (size_t)grow0 * 64 + 4 * cg) =
      make_float4(as0.x + sb4.x, as0.y + sb4.y, as0.z + sb4.z, as0.w + sb4.w);
  *(float4*)(Sk + (size_t)grow1 * 64 + 4 * cg) =
      make_float4(as1.x + sb4.x, as1.y + sb4.y, as1.z + sb4.z, as1.w + sb4.w);
}

// ---------------- attn layer1 fused with whsk2 (8 waves = 8 rows; x1 in LDS; tail-guarded exp)
__global__ __launch_bounds__(512) void attn_l1_kernel(
    const u16* __restrict__ Whh, const float* __restrict__ Sk,
    const int* __restrict__ cnt, const int* __restrict__ cols,
    const float* __restrict__ Wg2, const float* __restrict__ Sw2, const float* __restrict__ Sb2,
    u16* __restrict__ Whh2, float* __restrict__ Sk2) {
  __shared__ float wgt[4096];
  __shared__ float swt[4096];
  __shared__ float sbs[64];
  __shared__ float xl[8][64];
  int tid = threadIdx.x;
  int lane = tid & 63;
  int w = tid >> 6;  // 0..7
  int bid = blockIdx.x;
  int x = bid & 7;
  int gidx = bid >> 3;  // 0..255
  int b = x >> 1;
  int rowhalf = x & 1;
  int n = __builtin_amdgcn_readfirstlane(rowhalf * 2048 + gidx * 8 + w);
  int wid = b * NV + n;
  const u16* whhbase = Whh + (size_t)b * (NV * HD);
  int nn = __builtin_amdgcn_readfirstlane(cnt[n]);
  const int* cl = cols + n * CAP;
  int q = lane & 3;
  int gq = lane >> 2;

  for (int i = tid; i < 1024; i += 512) {
    ((float4*)wgt)[i] = ((const float4*)Wg2)[i];
    ((float4*)swt)[i] = ((const float4*)Sw2)[i];
  }
  if (tid < 64) sbs[tid] = Sb2[tid];

  const uint4* qr = (const uint4*)(whhbase + (size_t)n * HD);
  uint4 QA = qr[q];
  uint4 QB = qr[q + 4];

  float s[5], p[5];
  uint4 SA0, SB0, SA1, SB1, SA2, SB2;
#define SCORE_BLOCK(jb, SAv, SBv)                                                                \
  {                                                                                              \
    int j = (jb) * 16 + gq;                                                                      \
    int m = cl[j];                                                                               \
    const uint4* vr = (const uint4*)(whhbase + (size_t)m * HD);                                  \
    SAv = vr[q];                                                                                 \
    SBv = vr[q + 4];                                                                             \
    float t = 0.f;                                                                               \
    t = fdot2u(SAv.x, QA.x, t);                                                                  \
    t = fdot2u(SAv.y, QA.y, t);                                                                  \
    t = fdot2u(SAv.z, QA.z, t);                                                                  \
    t = fdot2u(SAv.w, QA.w, t);                                                                  \
    t = fdot2u(SBv.x, QB.x, t);                                                                  \
    t = fdot2u(SBv.y, QB.y, t);                                                                  \
    t = fdot2u(SBv.z, QB.z, t);                                                                  \
    t = fdot2u(SBv.w, QB.w, t);                                                                  \
    t += __shfl_xor(t, 1, 64);                                                                   \
    t += __shfl_xor(t, 2, 64);                                                                   \
    s[jb] = (j < nn) ? t * 0.125f : -1e30f;                                                      \
  }
  SCORE_BLOCK(0, SA0, SB0)
  SCORE_BLOCK(1, SA1, SB1)
  SCORE_BLOCK(2, SA2, SB2)
  s[3] = -1e30f;
  s[4] = -1e30f;
  bool tail = (nn > 48);
  if (tail) {
    uint4 TA, TB;
    SCORE_BLOCK(3, TA, TB)
    SCORE_BLOCK(4, TA, TB)
  }
#undef SCORE_BLOCK

  float mx = fmaxf(fmaxf(fmaxf(s[0], s[1]), fmaxf(s[2], s[3])), s[4]);
  mx = fmaxf(mx, __shfl_xor(mx, 4, 64));
  mx = fmaxf(mx, __shfl_xor(mx, 8, 64));
  mx = fmaxf(mx, __shfl_xor(mx, 16, 64));
  mx = fmaxf(mx, __shfl_xor(mx, 32, 64));
  float sum = 0.f;
#pragma unroll
  for (int jb = 0; jb < 3; ++jb) {
    p[jb] = (jb * 16 + gq < nn) ? __expf(s[jb] - mx) : 0.f;
    sum += p[jb];
  }
  p[3] = 0.f;
  p[4] = 0.f;
  if (tail) {
    p[3] = (48 + gq < nn) ? __expf(s[3] - mx) : 0.f;
    p[4] = (64 + gq < nn) ? __expf(s[4] - mx) : 0.f;
    sum += p[3] + p[4];
  }
  sum += __shfl_xor(sum, 4, 64);
  sum += __shfl_xor(sum, 8, 64);
  sum += __shfl_xor(sum, 16, 64);
  sum += __shfl_xor(sum, 32, 64);
  float inv = 1.f / sum;

  h2 aa[8];
#pragma unroll
  for (int k = 0; k < 8; ++k) aa[k] = h2{(_Float16)0, (_Float16)0};
#define PV_ACC(pp, Av, Bv)                                                                       \
  {                                                                                              \
    _Float16 pf = (_Float16)(pp);                                                                \
    h2 ph = {pf, pf};                                                                            \
    aa[0] += __builtin_bit_cast(h2, (Av).x) * ph;                                                \
    aa[1] += __builtin_bit_cast(h2, (Av).y) * ph;                                                \
    aa[2] += __builtin_bit_cast(h2, (Av).z) * ph;                                                \
    aa[3] += __builtin_bit_cast(h2, (Av).w) * ph;                                                \
    aa[4] += __builtin_bit_cast(h2, (Bv).x) * ph;                                                \
    aa[5] += __builtin_bit_cast(h2, (Bv).y) * ph;                                                \
    aa[6] += __builtin_bit_cast(h2, (Bv).z) * ph;                                                \
    aa[7] += __builtin_bit_cast(h2, (Bv).w) * ph;                                                \
  }
  PV_ACC(p[0], SA0, SB0)
  PV_ACC(p[1], SA1, SB1)
  PV_ACC(p[2], SA2, SB2)
  if (tail) {
    int m3 = cl[48 + gq];
    const uint4* vr3 = (const uint4*)(whhbase + (size_t)m3 * HD);
    uint4 A3 = vr3[q], B3 = vr3[q + 4];
    PV_ACC(p[3], A3, B3)
    if (nn > 64) {
      int m4 = cl[64 + gq];
      const uint4* vr4 = (const uint4*)(whhbase + (size_t)m4 * HD);
      uint4 A4 = vr4[q], B4 = vr4[q + 4];
      PV_ACC(p[4], A4, B4)
    }
  }
#undef PV_ACC

  bool g1 = (gq & 1) != 0;
  h2 bb[4];
#pragma unroll
  for (int i = 0; i < 4; ++i) {
    h2 k = g1 ? aa[i + 4] : aa[i];
    h2 u = g1 ? aa[i] : aa[i + 4];
    bb[i] = k + shx(u, 4);
  }
  bool g2 = (gq & 2) != 0;
  h2 cc[2];
#pragma unroll
  for (int i = 0; i < 2; ++i) {
    h2 k = g2 ? bb[i + 2] : bb[i];
    h2 u = g2 ? bb[i] : bb[i + 2];
    cc[i] = k + shx(u, 8);
  }
  bool g4 = (gq & 4) != 0;
  h2 dd;
  {
    h2 k = g4 ? cc[1] : cc[0];
    h2 u = g4 ? cc[0] : cc[1];
    dd = k + shx(u, 16);
  }
  dd = dd + shx(dd, 32);
  int a = 8 * q + 32 * (gq & 1) + 4 * ((gq >> 1) & 1) + 2 * ((gq >> 2) & 1);
  float f0 = (float)dd[0] * inv;
  float f1 = (float)dd[1] * inv;

  float2 sk2 = *(const float2*)(Sk + (size_t)wid * HD + a);
  float o0 = (f0 > 0.f ? f0 : (__expf(f0) - 1.f)) + sk2.x;
  float o1 = (f1 > 0.f ? f1 : (__expf(f1) - 1.f)) + sk2.y;
  if ((gq & 8) == 0) {
    xl[w][a] = o0;
    xl[w][a + 1] = o1;
  }
  __syncthreads();

  // ---- whsk2 tail: 2 waves compute Whh2/Sk2 for the block's 8 rows
  if (tid < 128) {
    int cg = tid & 15;
    int r = tid >> 4;
    float4 aw = make_float4(0, 0, 0, 0), as = make_float4(0, 0, 0, 0);
#pragma unroll 4
    for (int k = 0; k < 64; ++k) {
      float4 wv = *(const float4*)&wgt[k * 64 + 4 * cg];
      float4 sv = *(const float4*)&swt[k * 64 + 4 * cg];
      float xv = xl[r][k];
      aw.x = fmaf(xv, wv.x, aw.x); aw.y = fmaf(xv, wv.y, aw.y);
      aw.z = fmaf(xv, wv.z, aw.z); aw.w = fmaf(xv, wv.w, aw.w);
      as.x = fmaf(xv, sv.x, as.x); as.y = fmaf(xv, sv.y, as.y);
      as.z = fmaf(xv, sv.z, as.z); as.w = fmaf(xv, sv.w, as.w);
    }
    int n_r = rowhalf * 2048 + gidx * 8 + r;
    size_t wid_r = (size_t)(b * NV + n_r) * 64 + 4 * cg;
    float4 sb4 = *(const float4*)&sbs[4 * cg];
    ushort4 hh;
    hh.x = __builtin_bit_cast(u16, (_Float16)aw.x);
    hh.y = __builtin_bit_cast(u16, (_Float16)aw.y);
    hh.z = __builtin_bit_cast(u16, (_Float16)aw.z);
    hh.w = __builtin_bit_cast(u16, (_Float16)aw.w);
    *(ushort4*)(Whh2 + wid_r) = hh;
    *(float4*)(Sk2 + wid_r) =
        make_float4(as.x + sb4.x, as.y + sb4.y, as.z + sb4.z, as.w + sb4.w);
  }
}

// ---------------- attn layer2 (tail-guarded exp; fused readout)
__global__ __launch_bounds__(256) void attn_l2_kernel(
    const u16* __restrict__ Whh, const float* __restrict__ Sk,
    const int* __restrict__ cnt, const int* __restrict__ cols,
    const float* __restrict__ roW, const float* __restrict__ rob, float* __restrict__ out) {
  int tid = threadIdx.x;
  int lane = tid & 63;
  int w = tid >> 6;
  int bid = blockIdx.x;
  int x = bid & 7;
  int gidx = bid >> 3;
  int b = x >> 1;
  int n = __builtin_amdgcn_readfirstlane((x & 1) * 2048 + gidx * 4 + w);
  int wid = b * NV + n;
  const u16* whhbase = Whh + (size_t)b * (NV * HD);
  int nn = __builtin_amdgcn_readfirstlane(cnt[n]);
  const int* cl = cols + n * CAP;
  int q = lane & 3;
  int gq = lane >> 2;

  const uint4* qr = (const uint4*)(whhbase + (size_t)n * HD);
  uint4 QA = qr[q];
  uint4 QB = qr[q + 4];

  float s[5], p[5];
  uint4 SA0, SB0, SA1, SB1, SA2, SB2;
#define SCORE_BLOCK(jb, SAv, SBv)                                                                \
  {                                                                                              \
    int j = (jb) * 16 + gq;                                                                      \
    int m = cl[j];                                                                               \
    const uint4* vr = (const uint4*)(whhbase + (size_t)m * HD);                                  \
    SAv = vr[q];                                                                                 \
    SBv = vr[q + 4];                                                                             \
    float t = 0.f;                                                                               \
    t = fdot2u(SAv.x, QA.x, t);                                                                  \
    t = fdot2u(SAv.y, QA.y, t);                                                                  \
    t = fdot2u(SAv.z, QA.z, t);                                                                  \
    t = fdot2u(SAv.w, QA.w, t);                                                                  \
    t = fdot2u(SBv.x, QB.x, t);                                                                  \
    t = fdot2u(SBv.y, QB.y, t);                                                                  \
    t = fdot2u(SBv.z, QB.z, t);                                                                  \
    t = fdot2u(SBv.w, QB.w, t);                                                                  \
    t += __shfl_xor(t, 1, 64);                                                                   \
    t += __shfl_xor(t, 2, 64);                                                                   \
    s[jb] = (j < nn) ? t * 0.125f : -1e30f;                                                      \
  }
  SCORE_BLOCK(0, SA0, SB0)
  SCORE_BLOCK(1, SA1, SB1)
  SCORE_BLOCK(2, SA2, SB2)
  s[3] = -1e30f;
  s[4] = -1e30f;
  bool tail = (nn > 48);
  if (tail) {
    uint4 TA, TB;
    SCORE_BLOCK(3, TA, TB)
    SCORE_BLOCK(4, TA, TB)
  }
#undef SCORE_BLOCK

  float mx = fmaxf(fmaxf(fmaxf(s[0], s[1]), fmaxf(s[2], s[3])), s[4]);
  mx = fmaxf(mx, __shfl_xor(mx, 4, 64));
  mx = fmaxf(mx, __shfl_xor(mx, 8, 64));
  mx = fmaxf(mx, __shfl_xor(mx, 16, 64));
  mx = fmaxf(mx, __shfl_xor(mx, 32, 64));
  float sum = 0.f;
#pragma unroll
  for (int jb = 0; jb < 3; ++jb) {
    p[jb] = (jb * 16 + gq < nn) ? __expf(s[jb] - mx) : 0.f;
    sum += p[jb];
  }
  p[3] = 0.f;
  p[4] = 0.f;
  if (tail) {
    p[3] = (48 + gq < nn) ? __expf(s[3] - mx) : 0.f;
    p[4] = (64 + gq < nn) ? __expf(s[4] - mx) : 0.f;
    sum += p[3] + p[4];
  }
  sum += __shfl_xor(sum, 4, 64);
  sum += __shfl_xor(sum, 8, 64);
  sum += __shfl_xor(sum, 16, 64);
  sum += __shfl_xor(sum, 32, 64);
  float inv = 1.f / sum;

  h2 aa[8];
#pragma unroll
  for (int k = 0; k < 8; ++k) aa[k] = h2{(_Float16)0, (_Float16)0};
#define PV_ACC(pp, Av, Bv)                                                                       \
  {                                                                                              \
    _Float16 pf = (_Float16)(pp);                                                                \
    h2 ph = {pf, pf};                                                                            \
    aa[0] += __builtin_bit_cast(h2, (Av).x) * ph;                                                \
    aa[1] += __builtin_bit_cast(h2, (Av).y) * ph;                                                \
    aa[2] += __builtin_bit_cast(h2, (Av).z) * ph;                                                \
    aa[3] += __builtin_bit_cast(h2, (Av).w) * ph;                                                \
    aa[4] += __builtin_bit_cast(h2, (Bv).x) * ph;                                                \
    aa[5] += __builtin_bit_cast(h2, (Bv).y) * ph;                                                \
    aa[6] += __builtin_bit_cast(h2, (Bv).z) * ph;                                                \
    aa[7] += __builtin_bit_cast(h2, (Bv).w) * ph;                                                \
  }
  PV_ACC(p[0], SA0, SB0)
  PV_ACC(p[1], SA1, SB1)
  PV_ACC(p[2], SA2, SB2)
  if (tail) {
    int m3 = cl[48 + gq];
    const uint4* vr3 = (const uint4*)(whhbase + (size_t)m3 * HD);
    uint4 A3 = vr3[q], B3 = vr3[q + 4];
    PV_ACC(p[3], A3, B3)
    if (nn > 64) {
      int m4 = cl[64 + gq];
      const uint4* vr4 = (const uint4*)(whhbase + (size_t)m4 * HD);
      uint4 A4 = vr4[q], B4 = vr4[q + 4];
      PV_ACC(p[4], A4, B4)
    }
  }
#undef PV_ACC

  bool g1 = (gq & 1) != 0;
  h2 bb[4];
#pragma unroll
  for (int i = 0; i < 4; ++i) {
    h2 k = g1 ? aa[i + 4] : aa[i];
    h2 u = g1 ? aa[i] : aa[i + 4];
    bb[i] = k + shx(u, 4);
  }
  bool g2 = (gq & 2) != 0;
  h2 cc[2];
#pragma unroll
  for (int i = 0; i < 2; ++i) {
    h2 k = g2 ? bb[i + 2] : bb[i];
    h2 u = g2 ? bb[i] : bb[i + 2];
    cc[i] = k + shx(u, 8);
  }
  bool g4 = (gq & 4) != 0;
  h2 dd;
  {
    h2 k = g4 ? cc[1] : cc[0];
    h2 u = g4 ? cc[0] : cc[1];
    dd = k + shx(u, 16);
  }
  dd = dd + shx(dd, 32);
  int a = 8 * q + 32 * (gq & 1) + 4 * ((gq >> 1) & 1) + 2 * ((gq >> 2) & 1);
  float f0 = (float)dd[0] * inv;
  float f1 = (float)dd[1] * inv;

  float2 sk2 = *(const float2*)(Sk + (size_t)wid * HD + a);
  float2 ro2 = *(const float2*)(roW + a);
  float wsp = (f0 + sk2.x) * ro2.x + (f1 + sk2.y) * ro2.y;
  wsp += __shfl_xor(wsp, 1, 64);
  wsp += __shfl_xor(wsp, 2, 64);
  wsp += __shfl_xor(wsp, 4, 64);
  wsp += __shfl_xor(wsp, 8, 64);
  wsp += __shfl_xor(wsp, 16, 64);
  if (lane == 0) out[wid] = wsp + rob[0];
}

extern "C" void kernel_launch(void* const* d_in, const int* in_sizes, int n_in,
                              void* d_out, int out_size, void* d_ws, size_t ws_size,
                              hipStream_t stream) {
  const float* stim = (const float*)d_in[0];
  const float* adj  = (const float*)d_in[1];
  const float* W1   = (const float*)d_in[2];
  const float* b1   = (const float*)d_in[3];
  const float* lng  = (const float*)d_in[4];
  const float* lnb  = (const float*)d_in[5];
  const float* W2   = (const float*)d_in[6];
  const float* b2   = (const float*)d_in[7];
  const float* emb  = (const float*)d_in[8];
  const float* Wg1  = (const float*)d_in[9];
  const float* Wg2  = (const float*)d_in[10];
  const float* s1w  = (const float*)d_in[11];
  const float* s1b  = (const float*)d_in[12];
  const float* s2w  = (const float*)d_in[13];
  const float* s2b  = (const float*)d_in[14];
  const float* roW  = (const float*)d_in[15];
  const float* rob  = (const float*)d_in[16];
  float* out = (float*)d_out;

  char* ws = (char*)d_ws;
  float* part = (float*)(ws + 4096);       // 96 KB
  int*   cnt  = (int*)(ws + 131072);       // 4096 ints
  int*   cols = (int*)(ws + 147456);       // 4096*80 ints = 1.25 MB
  u16*   Whh2 = (u16*)(ws + 1572864);      // 2 MB  (layer2 f16 rows)
  float* Sk   = (float*)(ws + 5767168);    // 4 MB  (layer1 skip)
  float* Sk2  = (float*)(ws + 9961472);    // 4 MB  (layer2 skip)
  u16*   Whh  = (u16*)(ws + 14155776);     // 2 MB  (layer1 f16 rows)

  pre_kernel<<<dim3(NV + 96), dim3(256), 0, stream>>>(adj, cnt, cols, stim, W1, part);
  whsk1_kernel<<<dim3(NB * NV / 32), dim3(256), 0, stream>>>(part, b1, lng, lnb, W2, b2,
                                                             emb, Wg1, s1w, s1b, Whh, Sk);
  attn_l1_kernel<<<dim3(NB * NV / 8), dim3(512), 0, stream>>>(Whh, Sk, cnt, cols,
                                                              Wg2, s2w, s2b, Whh2, Sk2);
  attn_l2_kernel<<<dim3(NB * NV / 4), dim3(256), 0, stream>>>(Whh2, Sk2, cnt, cols,
                                                              roW, rob, out);
}